// Round 11
// baseline (442.912 us; speedup 1.0000x reference)
//
#include <hip/hip_runtime.h>
#include <math.h>
#include <float.h>

#define B_   16
#define N_   4096
#define CIN  3
#define COUT 64
#define KNN  20
#define EPS_ 1e-5

// ---------------------------------------------------------------------------
// Workspace layout (5.5MB proven-safe footprint):
//   [0,   216): double stats[27]    (Sum e[6], Sum e e^T upper-tri[21])
//   [256, 768): float scale[64], shift[64]
//   [1024, 1024 + B*N*KNN*4): int idx[B*N*KNN]           (5242880 B)
//   [5243904, +B*N*4): int perm[B*N]  (Morton row order)  (262144 B)
//
// r11 change (mlp only; knn/morton/bn_prep byte-identical to r10=440us):
//   mlp k-loop rotated one iteration: MFMA(k) consumes the h-tile written
//   in iter k-1, so the read->MFMA lgkmcnt wait no longer drains the 32
//   h-writes issued the same iteration (in-order LDS completion made that
//   a ~300cy stall every k). New order per iter:
//     [ds_read frags buf[k&1]] [setprio(1) MFMA k setprio(0)]
//     [h-compute k+1 -> write buf[(k+1)&1]] [prefetch coords k+2]
//   Arithmetic byte-identical (pure reorder) -> absmax must be unchanged.
//   setprio around MFMA: wave-independent kernel = the m191-positive case.
// ---------------------------------------------------------------------------

__device__ __forceinline__ unsigned expand10(unsigned v) {
    v = (v | (v << 16)) & 0x030000FFu;
    v = (v | (v << 8))  & 0x0300F00Fu;
    v = (v | (v << 4))  & 0x030C30C3u;
    v = (v | (v << 2))  & 0x09249249u;
    return v;
}
__device__ __forceinline__ unsigned quant10(float v) {
    int q = (int)((v + 4.0f) * 128.0f);
    return (unsigned)min(1023, max(0, q));
}

// ===========================================================================
// Kernel 0: per-batch Morton COUNTING sort (verbatim, verified)
// ===========================================================================
__global__ __launch_bounds__(1024) void morton_bucket_kernel(
    const float* __restrict__ x, int* __restrict__ perm)
{
    __shared__ int hist[1024];
    __shared__ int scanbuf[1024];
    __shared__ int offs[1024];
    const int b = blockIdx.x, tid = threadIdx.x;
    const float* xb = x + (size_t)b * N_ * CIN;

    hist[tid] = 0;
    __syncthreads();

    int keys[4];
#pragma unroll
    for (int i = 0; i < 4; ++i) {
        int p = tid + i * 1024;
        float v0 = xb[p * 3 + 0], v1 = xb[p * 3 + 1], v2 = xb[p * 3 + 2];
        unsigned m = (expand10(quant10(v0)) << 2) |
                     (expand10(quant10(v1)) << 1) |
                      expand10(quant10(v2));
        keys[i] = (int)(m >> 20);          // top 10 bits
        atomicAdd(&hist[keys[i]], 1);
    }
    __syncthreads();

    int v = hist[tid];
    scanbuf[tid] = v;
    __syncthreads();
    for (int off = 1; off < 1024; off <<= 1) {   // Hillis-Steele inclusive
        int t = (tid >= off) ? scanbuf[tid - off] : 0;
        __syncthreads();
        scanbuf[tid] += t;
        __syncthreads();
    }
    offs[tid] = scanbuf[tid] - v;                // exclusive base
    __syncthreads();

#pragma unroll
    for (int i = 0; i < 4; ++i) {
        int p = tid + i * 1024;
        int pos = atomicAdd(&offs[keys[i]], 1);
        perm[b * N_ + pos] = p;
    }
}

// ===========================================================================
// Kernel 1: exact-match KNN — byte-identical to r10 (326us, verified).
// ===========================================================================
__global__ __launch_bounds__(512) void knn_f64_kernel(
    const float* __restrict__ x, const int* __restrict__ perm,
    int* __restrict__ idx_out, double* __restrict__ stats)
{
    extern __shared__ __align__(16) char smem[];
    float4* pts = (float4*)smem;                            // {x,y,z,sqj}
    unsigned short* j16 = (unsigned short*)(smem + 65536);  // [4096] orig idx
    double* scr = (double*)smem;                            // merge view

    const int b    = blockIdx.y;
    const int tid  = threadIdx.x;
    const int wave = tid >> 6;
    const int lane = tid & 63;
    const int r    = wave >> 2;     // row-group 0..1
    const int q    = wave & 3;      // interleave class: positions p&3==q
    const float* xb = x + (size_t)b * N_ * CIN;

    for (int p = tid; p < N_; p += 512) {
        int j = perm[b * N_ + p];                // coalesced
        float v0 = xb[j * 3 + 0], v1 = xb[j * 3 + 1], v2 = xb[j * 3 + 2];
        float sq = __fadd_rn(__fadd_rn(__fmul_rn(v0, v0),
                                       __fmul_rn(v1, v1)),
                             __fmul_rn(v2, v2));
        pts[p] = make_float4(v0, v1, v2, sq);
        j16[p] = (unsigned short)j;
    }
    __syncthreads();

    const int rowg = blockIdx.x * 128 + r * 64;  // wave's first row pos
    const float4 xf = pts[rowg + lane];
    const int jrow  = j16[rowg + lane];
    const float sqi = xf.w;                      // staged, bit-identical

    auto mkd = [&](float4 p) -> float {
        float dot = __fadd_rn(__fadd_rn(__fmul_rn(xf.x, p.x),
                                        __fmul_rn(xf.y, p.y)),
                              __fmul_rn(xf.z, p.z));
        return __fsub_rn(__fadd_rn(sqi, p.w), __fmul_rn(2.0f, dot));
    };
    auto sortable = [&](float d) -> unsigned {
        unsigned u = __float_as_uint(d);
        return u ^ (0x80000000u | (unsigned)((int)u >> 31));
    };

    double bk[KNN];
#pragma unroll
    for (int k = 0; k < KNN; ++k) bk[k] = 1e300;     // sentinels (sorted)

    auto insert = [&](double key) {                  // VERBATIM verified
        if (key < bk[KNN - 1]) {
            double m = key;                  // carries max(bk_old[i-1], key)
#pragma unroll
            for (int k = 0; k < KNN; ++k) {
                double old = bk[k];
                bk[k] = fmin(m, old);
                m     = fmax(old, m);
            }
        }
    };

    const int ta = rowg >> 2;            // wave-uniform anchor (SGPR math)
#pragma unroll
    for (int k = 0; k < KNN; ++k) {
        int p = 4 * ((ta + k) & 1023) + q;
        float4 a = pts[p];
        insert(fma((double)sortable(mkd(a)), 4096.0,
                   (double)(unsigned)j16[p]));
    }

    // d19f = exact d of the current 20th-best key (r4-verified decode);
    // refreshed only where bk can change (triggered bodies) -> stale
    // between bodies = over-enter only (insert re-checks the full key).
    float d19f;
    {
        unsigned s19 = (unsigned)trunc(bk[KNN - 1] * (1.0 / 4096.0));
        unsigned u = (s19 >= 0x80000000u) ? (s19 ^ 0x80000000u) : ~s19;
        d19f = __uint_as_float(u);
    }

    for (int s = 0; s < 1024; s += 4) {
        int v0 = ((s + 0) * 509) & 1023;
        int v1 = ((s + 1) * 509) & 1023;
        int v2 = ((s + 2) * 509) & 1023;
        int v3 = ((s + 3) * 509) & 1023;
        int p0 = 4 * ((ta + v0) & 1023) + q;
        int p1 = 4 * ((ta + v1) & 1023) + q;
        int p2 = 4 * ((ta + v2) & 1023) + q;
        int p3 = 4 * ((ta + v3) & 1023) + q;
        float4 a0 = pts[p0];
        float4 a1 = pts[p1];
        float4 a2 = pts[p2];
        float4 a3 = pts[p3];
        float d0 = mkd(a0), d1 = mkd(a1), d2 = mkd(a2), d3 = mkd(a3);
        // prefill positions masked with +INF: its key exceeds any real key.
        d0 = (v0 < 20) ? INFINITY : d0;
        d1 = (v1 < 20) ? INFINITY : d1;
        d2 = (v2 < 20) ? INFINITY : d2;
        d3 = (v3 < 20) ? INFINITY : d3;
        if ((d0 <= d19f) | (d1 <= d19f) | (d2 <= d19f) | (d3 <= d19f)) {
            unsigned j0 = j16[p0], j1 = j16[p1], j2 = j16[p2], j3 = j16[p3];
            insert(fma((double)sortable(d0), 4096.0, (double)j0));
            insert(fma((double)sortable(d1), 4096.0, (double)j1));
            insert(fma((double)sortable(d2), 4096.0, (double)j2));
            insert(fma((double)sortable(d3), 4096.0, (double)j3));
            unsigned s19 = (unsigned)trunc(bk[KNN - 1] * (1.0 / 4096.0));
            unsigned u = (s19 >= 0x80000000u) ? (s19 ^ 0x80000000u) : ~s19;
            d19f = __uint_as_float(u);
        }
    }
    __syncthreads();    // scans done; pts dead (xf in regs) -> scr valid

    if (q & 1) {
        int base = ((r * 2 + (q >> 1)) * 64 + lane) * KNN;
#pragma unroll
        for (int k = 0; k < KNN; ++k) scr[base + k] = bk[k];
    }
    __syncthreads();
    if (!(q & 1)) {                 // q0 absorbs q1; q2 absorbs q3
        int base = ((r * 2 + (q >> 1)) * 64 + lane) * KNN;
#pragma unroll
        for (int k = 0; k < KNN; ++k) insert(scr[base + k]);
    }
    __syncthreads();
    if (q == 2) {
        int base = ((r * 2 + 1) * 64 + lane) * KNN;
#pragma unroll
        for (int k = 0; k < KNN; ++k) scr[base + k] = bk[k];
    }
    __syncthreads();
    if (q == 0) {
        int base = ((r * 2 + 1) * 64 + lane) * KNN;
#pragma unroll
        for (int k = 0; k < KNN; ++k) insert(scr[base + k]);

        const long long row = (long long)b * N_ + jrow;
        int bi[KNN];
#pragma unroll
        for (int k = 0; k < KNN; ++k) {
            double sp = trunc(bk[k] * (1.0 / 4096.0));
            bi[k] = (int)(bk[k] - sp * 4096.0);
        }
#pragma unroll
        for (int k = 0; k < KNN; ++k) idx_out[row * KNN + k] = bi[k];

        float acc[27];
#pragma unroll
        for (int t = 0; t < 27; ++t) acc[t] = 0.0f;
#pragma unroll
        for (int k = 0; k < KNN; ++k) {
            const float* pj = xb + bi[k] * 3;
            float e[6] = { xf.x, xf.y, xf.z,
                           pj[0] - xf.x, pj[1] - xf.y, pj[2] - xf.z };
            int t = 6;
#pragma unroll
            for (int a = 0; a < 6; ++a) {
                acc[a] += e[a];
#pragma unroll
                for (int bb = a; bb < 6; ++bb) acc[t++] += e[a] * e[bb];
            }
        }
#pragma unroll
        for (int t = 0; t < 27; ++t) {
            float v = acc[t];
            v += __shfl_down(v, 32); v += __shfl_down(v, 16);
            v += __shfl_down(v, 8);  v += __shfl_down(v, 4);
            v += __shfl_down(v, 2);  v += __shfl_down(v, 1);
            acc[t] = v;
        }
        if (lane == 0) {
#pragma unroll
            for (int t = 0; t < 27; ++t) atomicAdd(&stats[t], (double)acc[t]);
        }
    }
}

// ===========================================================================
// Kernel 2: fold stats -> per-channel scale/shift (unchanged, verified)
// ===========================================================================
__global__ void bn_prep_kernel(
    const double* __restrict__ stats,
    const float* __restrict__ w1, const float* __restrict__ b1,
    const float* __restrict__ gamma, const float* __restrict__ beta,
    float* __restrict__ scale_shift)
{
    const int c = threadIdx.x;
    double s[6], S[6][6];
#pragma unroll
    for (int a = 0; a < 6; ++a) s[a] = stats[a];
    int t = 6;
#pragma unroll
    for (int a = 0; a < 6; ++a)
#pragma unroll
        for (int bb = a; bb < 6; ++bb) { S[a][bb] = stats[t]; S[bb][a] = stats[t]; ++t; }

    const double M = (double)B_ * N_ * KNN;
    double wc[6];
#pragma unroll
    for (int j = 0; j < 6; ++j) wc[j] = (double)w1[j * COUT + c];
    const double b1c = (double)b1[c];

    double sw = 0.0;
#pragma unroll
    for (int j = 0; j < 6; ++j) sw += s[j] * wc[j];
    double mean = sw / M + b1c;

    double qq = 0.0;
#pragma unroll
    for (int a = 0; a < 6; ++a)
#pragma unroll
        for (int bb = 0; bb < 6; ++bb) qq += S[a][bb] * wc[a] * wc[bb];
    double ex2 = (qq + 2.0 * b1c * sw) / M + b1c * b1c;
    double var = ex2 - mean * mean;

    double sc = (double)gamma[c] / sqrt(var + (double)EPS_);
    double sh = (double)beta[c] - mean * sc;
    scale_shift[c]        = (float)sc;
    scale_shift[COUT + c] = (float)sh;
}

// ===========================================================================
// Kernel 3: fused edge->lin1->BN->ReLU->lin2->max via split-bf16 MFMA.
// r11: rotated software pipeline — MFMA(k) consumes buf written in iter
// k-1; h-writes for k+1 and coord prefetch for k+2 issue AFTER the MFMA
// block. Arithmetic byte-identical to r10.
// ===========================================================================
typedef __attribute__((ext_vector_type(8))) short short8;
typedef __attribute__((ext_vector_type(4))) float f32x4;

__device__ __forceinline__ unsigned short f2bf_rn(float f) {
    unsigned u = __float_as_uint(f);
    unsigned lsb = (u >> 16) & 1u;
    return (unsigned short)((u + 0x7FFFu + lsb) >> 16);
}
__device__ __forceinline__ float bf2f(unsigned short h) {
    return __uint_as_float(((unsigned)h) << 16);
}

__global__ __launch_bounds__(256) void mlp_max_kernel(
    const float* __restrict__ x, const int* __restrict__ idx,
    const float* __restrict__ w1, const float* __restrict__ b1,
    const float* __restrict__ scale_shift,
    const float* __restrict__ w2, const float* __restrict__ b2,
    float* __restrict__ out)
{
    __shared__ __align__(16) unsigned short hbuf[4][2][16][136];  // 34.8KB
    __shared__ int idxs[4][320];                                  // +5KB

    const int tid  = threadIdx.x;
    const int wv   = tid >> 6;
    const int lane = tid & 63;
    const int g    = lane >> 4;      // 16-lane group (k-chunk select)
    const int r15  = lane & 15;      // row (A) / col (B,C) within tile

    const int R     = (blockIdx.x * 4 + wv) * 16;   // wave's first row
    const int bbase = (R >> 12) << 12;              // batch slab start row

    // ---- stage this wave's idx block into LDS (coalesced, wave-private) --
    {
        const int* ip = idx + (size_t)R * KNN;
#pragma unroll
        for (int i = 0; i < 5; ++i)
            idxs[wv][lane + i * 64] = ip[lane + i * 64];
    }

    const int c  = lane;
    const float sc = scale_shift[c];
    const float sh = scale_shift[COUT + c];
    float w1p[6];
#pragma unroll
    for (int j = 0; j < 6; ++j) w1p[j] = w1[j * COUT + c] * sc;
    const float b1p = fmaf(b1[c], sc, sh);
    const float dw0 = w1p[0] - w1p[3];
    const float dw1 = w1p[1] - w1p[4];
    const float dw2 = w1p[2] - w1p[5];

    short8 Wh[2][4], Wl[2][4];
#pragma unroll
    for (int t = 0; t < 2; ++t)
#pragma unroll
        for (int n = 0; n < 4; ++n) {
            short8 hv, lv;
#pragma unroll
            for (int jj = 0; jj < 8; ++jj) {
                float w = w2[(t * 32 + g * 8 + jj) * COUT + n * 16 + r15];
                unsigned short hi = f2bf_rn(w);
                unsigned short lo = f2bf_rn(w - bf2f(hi));
                hv[jj] = (short)hi;
                lv[jj] = (short)lo;
            }
            Wh[t][n] = hv;
            Wl[t][n] = lv;
        }

    float base[16];
#pragma unroll
    for (int r = 0; r < 16; ++r) {
        const float* pi = x + (size_t)(R + r) * 3;
        float v = b1p;
        v = fmaf(pi[0], dw0, v);
        v = fmaf(pi[1], dw1, v);
        v = fmaf(pi[2], dw2, v);
        base[r] = v;
    }

    float px[16], py[16], pz[16];

    // helper lambdas (inlined): h-compute+write for neighbor set in px/py/pz
    auto compute_h_to = [&](unsigned short* hb) {
#pragma unroll
        for (int r = 0; r < 16; ++r) {
            float h = base[r];
            h = fmaf(px[r], w1p[3], h);
            h = fmaf(py[r], w1p[4], h);
            h = fmaf(pz[r], w1p[5], h);
            h = fmaxf(h, 0.0f);
            unsigned hu = __float_as_uint(h);
            unsigned short hi = (unsigned short)(hu >> 16);
            float rem = h - __uint_as_float(hu & 0xFFFF0000u);
            unsigned short lo = (unsigned short)(__float_as_uint(rem) >> 16);
            hb[r * 136 + c]      = hi;
            hb[r * 136 + 64 + c] = lo;
        }
    };
    auto prefetch_k = [&](int kk) {
#pragma unroll
        for (int r = 0; r < 16; ++r) {
            int j = idxs[wv][r * KNN + kk];           // LDS, wave-uniform
            const float* pj = x + (size_t)(bbase + j) * 3;
            px[r] = pj[0]; py[r] = pj[1]; pz[r] = pj[2];
        }
    };

    // prologue: h[0] -> buf0; coords[1] in px
    prefetch_k(0);
    compute_h_to(&hbuf[wv][0][0][0]);
    prefetch_k(1);

    f32x4 mx[4];
#pragma unroll
    for (int n = 0; n < 4; ++n) {
        mx[n][0] = -INFINITY; mx[n][1] = -INFINITY;
        mx[n][2] = -INFINITY; mx[n][3] = -INFINITY;
    }

    for (int k = 0; k < KNN; ++k) {
        // (1) A-frags of k from buf[k&1] (written in iter k-1 / prologue)
        const unsigned short* rpnt = &hbuf[wv][k & 1][0][0] + r15 * 136;
        short8 Ah0 = *(const short8*)(rpnt + g * 8);
        short8 Ah1 = *(const short8*)(rpnt + 32 + g * 8);
        short8 Al0 = *(const short8*)(rpnt + 64 + g * 8);
        short8 Al1 = *(const short8*)(rpnt + 96 + g * 8);

        // (2) MFMA k + fmax (waits only on the 4 reads; prev writes long
        //     retired). setprio favors the MFMA wave on the CU scheduler.
        __builtin_amdgcn_s_setprio(1);
#pragma unroll
        for (int n = 0; n < 4; ++n) {
            f32x4 a = {0.0f, 0.0f, 0.0f, 0.0f};
            a = __builtin_amdgcn_mfma_f32_16x16x32_bf16(Ah0, Wh[0][n], a, 0, 0, 0);
            a = __builtin_amdgcn_mfma_f32_16x16x32_bf16(Ah1, Wh[1][n], a, 0, 0, 0);
            a = __builtin_amdgcn_mfma_f32_16x16x32_bf16(Al0, Wh[0][n], a, 0, 0, 0);
            a = __builtin_amdgcn_mfma_f32_16x16x32_bf16(Al1, Wh[1][n], a, 0, 0, 0);
            a = __builtin_amdgcn_mfma_f32_16x16x32_bf16(Ah0, Wl[0][n], a, 0, 0, 0);
            a = __builtin_amdgcn_mfma_f32_16x16x32_bf16(Ah1, Wl[1][n], a, 0, 0, 0);
            mx[n][0] = fmaxf(mx[n][0], a[0]);
            mx[n][1] = fmaxf(mx[n][1], a[1]);
            mx[n][2] = fmaxf(mx[n][2], a[2]);
            mx[n][3] = fmaxf(mx[n][3], a[3]);
        }
        __builtin_amdgcn_s_setprio(0);

        // (3) h for k+1 -> the other buffer (drains during next iter's MFMA)
        if (k + 1 < KNN) {
            compute_h_to(&hbuf[wv][(k + 1) & 1][0][0]);
        }
        // (4) coords for k+2
        if (k + 2 < KNN) {
            prefetch_k(k + 2);
        }
    }

    float b2v[4];
#pragma unroll
    for (int n = 0; n < 4; ++n) b2v[n] = b2[n * 16 + r15];
#pragma unroll
    for (int n = 0; n < 4; ++n)
#pragma unroll
        for (int rr = 0; rr < 4; ++rr)
            out[(size_t)(R + g * 4 + rr) * COUT + n * 16 + r15] =
                mx[n][rr] + b2v[n];
}

// ===========================================================================
extern "C" void kernel_launch(void* const* d_in, const int* in_sizes, int n_in,
                              void* d_out, int out_size, void* d_ws, size_t ws_size,
                              hipStream_t stream)
{
    const float* x     = (const float*)d_in[0];
    const float* w1    = (const float*)d_in[2];
    const float* b1    = (const float*)d_in[3];
    const float* gamma = (const float*)d_in[4];
    const float* beta  = (const float*)d_in[5];
    const float* w2    = (const float*)d_in[6];
    const float* b2    = (const float*)d_in[7];
    float* out = (float*)d_out;

    char*   ws          = (char*)d_ws;
    double* stats       = (double*)ws;
    float*  scale_shift = (float*)(ws + 256);
    int*    idx         = (int*)(ws + 1024);
    int*    perm        = (int*)(ws + 1024 + (size_t)B_ * N_ * KNN * 4);

    // one-time opt-in for >64KB dynamic LDS; host-side, graph-capture-safe.
    static int _lds_once = []() {
        (void)hipFuncSetAttribute((const void*)knn_f64_kernel,
                                  hipFuncAttributeMaxDynamicSharedMemorySize,
                                  131072);
        return 0;
    }();
    (void)_lds_once;

    hipMemsetAsync(stats, 0, 27 * sizeof(double), stream);
    morton_bucket_kernel<<<B_, 1024, 0, stream>>>(x, perm);
    knn_f64_kernel<<<dim3(32, 16), 512, 73728, stream>>>(x, perm, idx, stats);
    bn_prep_kernel<<<1, COUT, 0, stream>>>(stats, w1, b1, gamma, beta, scale_shift);
    mlp_max_kernel<<<(B_ * N_) / 64, 256, 0, stream>>>(x, idx, w1, b1, scale_shift,
                                                       w2, b2, out);
}

// Round 12
// 437.738 us; speedup vs baseline: 1.0118x; 1.0118x over previous
//
#include <hip/hip_runtime.h>
#include <math.h>
#include <float.h>

#define B_   16
#define N_   4096
#define CIN  3
#define COUT 64
#define KNN  20
#define EPS_ 1e-5

// ---------------------------------------------------------------------------
// Workspace layout (5.5MB proven-safe footprint):
//   [0,   216): double stats[27]    (Sum e[6], Sum e e^T upper-tri[21])
//   [256, 768): float scale[64], shift[64]
//   [1024, 1024 + B*N*KNN*4): int idx[B*N*KNN]           (5242880 B)
//   [5243904, +B*N*4): int perm[B*N]  (Morton row order)  (262144 B)
//
// r12 changes:
//   knn: byte-identical to r10 (326us verified local minimum — frozen).
//   morton: + stats zeroing folded in (replaces hipMemsetAsync dispatch).
//   mlp: lane-parallel gather. Old: per k, 16 sequential WAVE-UNIFORM
//        load chains (LDS idx -> addr -> 3 global loads of the SAME 12B on
//        all 64 lanes) = 48 wave-insts/k of issue + chained latency; r11
//        proved the LDS write->read drain was NOT the limiter, leaving this
//        chain as the structural suspect for mlp's ~10x-over-floor time.
//        New: 64 lanes map to (16 rows x 4 k-slots); each lane gathers its
//        own neighbor's coords (64 independent scattered loads), stages to
//        sbuf[wv][grp&1][ks][r] (wave-private float4, double-buffered per
//        4-k group, issued one group ahead); consume via uniform broadcast
//        ds_read_b128. Values and fma order identical -> absmax unchanged.
//        hbuf collapsed to single buffer (r10~r11: drain is a non-issue).
// ---------------------------------------------------------------------------

__device__ __forceinline__ unsigned expand10(unsigned v) {
    v = (v | (v << 16)) & 0x030000FFu;
    v = (v | (v << 8))  & 0x0300F00Fu;
    v = (v | (v << 4))  & 0x030C30C3u;
    v = (v | (v << 2))  & 0x09249249u;
    return v;
}
__device__ __forceinline__ unsigned quant10(float v) {
    int q = (int)((v + 4.0f) * 128.0f);
    return (unsigned)min(1023, max(0, q));
}

// ===========================================================================
// Kernel 0: per-batch Morton COUNTING sort (verified) + stats zeroing
// ===========================================================================
__global__ __launch_bounds__(1024) void morton_bucket_kernel(
    const float* __restrict__ x, int* __restrict__ perm,
    double* __restrict__ stats)
{
    __shared__ int hist[1024];
    __shared__ int scanbuf[1024];
    __shared__ int offs[1024];
    const int b = blockIdx.x, tid = threadIdx.x;
    const float* xb = x + (size_t)b * N_ * CIN;

    if (b == 0 && tid < 27) stats[tid] = 0.0;    // replaces hipMemsetAsync;
                                                 // stream-ordered before knn

    hist[tid] = 0;
    __syncthreads();

    int keys[4];
#pragma unroll
    for (int i = 0; i < 4; ++i) {
        int p = tid + i * 1024;
        float v0 = xb[p * 3 + 0], v1 = xb[p * 3 + 1], v2 = xb[p * 3 + 2];
        unsigned m = (expand10(quant10(v0)) << 2) |
                     (expand10(quant10(v1)) << 1) |
                      expand10(quant10(v2));
        keys[i] = (int)(m >> 20);          // top 10 bits
        atomicAdd(&hist[keys[i]], 1);
    }
    __syncthreads();

    int v = hist[tid];
    scanbuf[tid] = v;
    __syncthreads();
    for (int off = 1; off < 1024; off <<= 1) {   // Hillis-Steele inclusive
        int t = (tid >= off) ? scanbuf[tid - off] : 0;
        __syncthreads();
        scanbuf[tid] += t;
        __syncthreads();
    }
    offs[tid] = scanbuf[tid] - v;                // exclusive base
    __syncthreads();

#pragma unroll
    for (int i = 0; i < 4; ++i) {
        int p = tid + i * 1024;
        int pos = atomicAdd(&offs[keys[i]], 1);
        perm[b * N_ + pos] = p;
    }
}

// ===========================================================================
// Kernel 1: exact-match KNN — byte-identical to r10 (326us, verified).
// ===========================================================================
__global__ __launch_bounds__(512) void knn_f64_kernel(
    const float* __restrict__ x, const int* __restrict__ perm,
    int* __restrict__ idx_out, double* __restrict__ stats)
{
    extern __shared__ __align__(16) char smem[];
    float4* pts = (float4*)smem;                            // {x,y,z,sqj}
    unsigned short* j16 = (unsigned short*)(smem + 65536);  // [4096] orig idx
    double* scr = (double*)smem;                            // merge view

    const int b    = blockIdx.y;
    const int tid  = threadIdx.x;
    const int wave = tid >> 6;
    const int lane = tid & 63;
    const int r    = wave >> 2;     // row-group 0..1
    const int q    = wave & 3;      // interleave class: positions p&3==q
    const float* xb = x + (size_t)b * N_ * CIN;

    for (int p = tid; p < N_; p += 512) {
        int j = perm[b * N_ + p];                // coalesced
        float v0 = xb[j * 3 + 0], v1 = xb[j * 3 + 1], v2 = xb[j * 3 + 2];
        float sq = __fadd_rn(__fadd_rn(__fmul_rn(v0, v0),
                                       __fmul_rn(v1, v1)),
                             __fmul_rn(v2, v2));
        pts[p] = make_float4(v0, v1, v2, sq);
        j16[p] = (unsigned short)j;
    }
    __syncthreads();

    const int rowg = blockIdx.x * 128 + r * 64;  // wave's first row pos
    const float4 xf = pts[rowg + lane];
    const int jrow  = j16[rowg + lane];
    const float sqi = xf.w;                      // staged, bit-identical

    auto mkd = [&](float4 p) -> float {
        float dot = __fadd_rn(__fadd_rn(__fmul_rn(xf.x, p.x),
                                        __fmul_rn(xf.y, p.y)),
                              __fmul_rn(xf.z, p.z));
        return __fsub_rn(__fadd_rn(sqi, p.w), __fmul_rn(2.0f, dot));
    };
    auto sortable = [&](float d) -> unsigned {
        unsigned u = __float_as_uint(d);
        return u ^ (0x80000000u | (unsigned)((int)u >> 31));
    };

    double bk[KNN];
#pragma unroll
    for (int k = 0; k < KNN; ++k) bk[k] = 1e300;     // sentinels (sorted)

    auto insert = [&](double key) {                  // VERBATIM verified
        if (key < bk[KNN - 1]) {
            double m = key;                  // carries max(bk_old[i-1], key)
#pragma unroll
            for (int k = 0; k < KNN; ++k) {
                double old = bk[k];
                bk[k] = fmin(m, old);
                m     = fmax(old, m);
            }
        }
    };

    const int ta = rowg >> 2;            // wave-uniform anchor (SGPR math)
#pragma unroll
    for (int k = 0; k < KNN; ++k) {
        int p = 4 * ((ta + k) & 1023) + q;
        float4 a = pts[p];
        insert(fma((double)sortable(mkd(a)), 4096.0,
                   (double)(unsigned)j16[p]));
    }

    // d19f = exact d of the current 20th-best key (r4-verified decode);
    // refreshed only where bk can change (triggered bodies) -> stale
    // between bodies = over-enter only (insert re-checks the full key).
    float d19f;
    {
        unsigned s19 = (unsigned)trunc(bk[KNN - 1] * (1.0 / 4096.0));
        unsigned u = (s19 >= 0x80000000u) ? (s19 ^ 0x80000000u) : ~s19;
        d19f = __uint_as_float(u);
    }

    for (int s = 0; s < 1024; s += 4) {
        int v0 = ((s + 0) * 509) & 1023;
        int v1 = ((s + 1) * 509) & 1023;
        int v2 = ((s + 2) * 509) & 1023;
        int v3 = ((s + 3) * 509) & 1023;
        int p0 = 4 * ((ta + v0) & 1023) + q;
        int p1 = 4 * ((ta + v1) & 1023) + q;
        int p2 = 4 * ((ta + v2) & 1023) + q;
        int p3 = 4 * ((ta + v3) & 1023) + q;
        float4 a0 = pts[p0];
        float4 a1 = pts[p1];
        float4 a2 = pts[p2];
        float4 a3 = pts[p3];
        float d0 = mkd(a0), d1 = mkd(a1), d2 = mkd(a2), d3 = mkd(a3);
        // prefill positions masked with +INF: its key exceeds any real key.
        d0 = (v0 < 20) ? INFINITY : d0;
        d1 = (v1 < 20) ? INFINITY : d1;
        d2 = (v2 < 20) ? INFINITY : d2;
        d3 = (v3 < 20) ? INFINITY : d3;
        if ((d0 <= d19f) | (d1 <= d19f) | (d2 <= d19f) | (d3 <= d19f)) {
            unsigned j0 = j16[p0], j1 = j16[p1], j2 = j16[p2], j3 = j16[p3];
            insert(fma((double)sortable(d0), 4096.0, (double)j0));
            insert(fma((double)sortable(d1), 4096.0, (double)j1));
            insert(fma((double)sortable(d2), 4096.0, (double)j2));
            insert(fma((double)sortable(d3), 4096.0, (double)j3));
            unsigned s19 = (unsigned)trunc(bk[KNN - 1] * (1.0 / 4096.0));
            unsigned u = (s19 >= 0x80000000u) ? (s19 ^ 0x80000000u) : ~s19;
            d19f = __uint_as_float(u);
        }
    }
    __syncthreads();    // scans done; pts dead (xf in regs) -> scr valid

    if (q & 1) {
        int base = ((r * 2 + (q >> 1)) * 64 + lane) * KNN;
#pragma unroll
        for (int k = 0; k < KNN; ++k) scr[base + k] = bk[k];
    }
    __syncthreads();
    if (!(q & 1)) {                 // q0 absorbs q1; q2 absorbs q3
        int base = ((r * 2 + (q >> 1)) * 64 + lane) * KNN;
#pragma unroll
        for (int k = 0; k < KNN; ++k) insert(scr[base + k]);
    }
    __syncthreads();
    if (q == 2) {
        int base = ((r * 2 + 1) * 64 + lane) * KNN;
#pragma unroll
        for (int k = 0; k < KNN; ++k) scr[base + k] = bk[k];
    }
    __syncthreads();
    if (q == 0) {
        int base = ((r * 2 + 1) * 64 + lane) * KNN;
#pragma unroll
        for (int k = 0; k < KNN; ++k) insert(scr[base + k]);

        const long long row = (long long)b * N_ + jrow;
        int bi[KNN];
#pragma unroll
        for (int k = 0; k < KNN; ++k) {
            double sp = trunc(bk[k] * (1.0 / 4096.0));
            bi[k] = (int)(bk[k] - sp * 4096.0);
        }
#pragma unroll
        for (int k = 0; k < KNN; ++k) idx_out[row * KNN + k] = bi[k];

        float acc[27];
#pragma unroll
        for (int t = 0; t < 27; ++t) acc[t] = 0.0f;
#pragma unroll
        for (int k = 0; k < KNN; ++k) {
            const float* pj = xb + bi[k] * 3;
            float e[6] = { xf.x, xf.y, xf.z,
                           pj[0] - xf.x, pj[1] - xf.y, pj[2] - xf.z };
            int t = 6;
#pragma unroll
            for (int a = 0; a < 6; ++a) {
                acc[a] += e[a];
#pragma unroll
                for (int bb = a; bb < 6; ++bb) acc[t++] += e[a] * e[bb];
            }
        }
#pragma unroll
        for (int t = 0; t < 27; ++t) {
            float v = acc[t];
            v += __shfl_down(v, 32); v += __shfl_down(v, 16);
            v += __shfl_down(v, 8);  v += __shfl_down(v, 4);
            v += __shfl_down(v, 2);  v += __shfl_down(v, 1);
            acc[t] = v;
        }
        if (lane == 0) {
#pragma unroll
            for (int t = 0; t < 27; ++t) atomicAdd(&stats[t], (double)acc[t]);
        }
    }
}

// ===========================================================================
// Kernel 2: fold stats -> per-channel scale/shift (unchanged, verified)
// ===========================================================================
__global__ void bn_prep_kernel(
    const double* __restrict__ stats,
    const float* __restrict__ w1, const float* __restrict__ b1,
    const float* __restrict__ gamma, const float* __restrict__ beta,
    float* __restrict__ scale_shift)
{
    const int c = threadIdx.x;
    double s[6], S[6][6];
#pragma unroll
    for (int a = 0; a < 6; ++a) s[a] = stats[a];
    int t = 6;
#pragma unroll
    for (int a = 0; a < 6; ++a)
#pragma unroll
        for (int bb = a; bb < 6; ++bb) { S[a][bb] = stats[t]; S[bb][a] = stats[t]; ++t; }

    const double M = (double)B_ * N_ * KNN;
    double wc[6];
#pragma unroll
    for (int j = 0; j < 6; ++j) wc[j] = (double)w1[j * COUT + c];
    const double b1c = (double)b1[c];

    double sw = 0.0;
#pragma unroll
    for (int j = 0; j < 6; ++j) sw += s[j] * wc[j];
    double mean = sw / M + b1c;

    double qq = 0.0;
#pragma unroll
    for (int a = 0; a < 6; ++a)
#pragma unroll
        for (int bb = 0; bb < 6; ++bb) qq += S[a][bb] * wc[a] * wc[bb];
    double ex2 = (qq + 2.0 * b1c * sw) / M + b1c * b1c;
    double var = ex2 - mean * mean;

    double sc = (double)gamma[c] / sqrt(var + (double)EPS_);
    double sh = (double)beta[c] - mean * sc;
    scale_shift[c]        = (float)sc;
    scale_shift[COUT + c] = (float)sh;
}

// ===========================================================================
// Kernel 3: fused edge->lin1->BN->ReLU->lin2->max via split-bf16 MFMA.
// r12: lane-parallel gather (64 lanes = 16 rows x 4 k-slots) staged to a
// wave-private double-buffered LDS group buffer; consume via uniform
// broadcast ds_read_b128. Values/fma order identical to r10.
// ===========================================================================
typedef __attribute__((ext_vector_type(8))) short short8;
typedef __attribute__((ext_vector_type(4))) float f32x4;

__device__ __forceinline__ unsigned short f2bf_rn(float f) {
    unsigned u = __float_as_uint(f);
    unsigned lsb = (u >> 16) & 1u;
    return (unsigned short)((u + 0x7FFFu + lsb) >> 16);
}
__device__ __forceinline__ float bf2f(unsigned short h) {
    return __uint_as_float(((unsigned)h) << 16);
}

__global__ __launch_bounds__(256) void mlp_max_kernel(
    const float* __restrict__ x, const int* __restrict__ idx,
    const float* __restrict__ w1, const float* __restrict__ b1,
    const float* __restrict__ scale_shift,
    const float* __restrict__ w2, const float* __restrict__ b2,
    float* __restrict__ out)
{
    __shared__ __align__(16) unsigned short hbuf[4][16][136];   // 17.4KB
    __shared__ int idxs[4][320];                                // 5KB
    __shared__ __align__(16) float4 sbuf[4][2][4][16];          // 8KB

    const int tid  = threadIdx.x;
    const int wv   = tid >> 6;
    const int lane = tid & 63;
    const int g    = lane >> 4;      // 16-lane group (k-chunk select)
    const int r15  = lane & 15;      // row (A) / col (B,C) within tile

    const int R     = (blockIdx.x * 4 + wv) * 16;   // wave's first row
    const int bbase = (R >> 12) << 12;              // batch slab start row

    // ---- stage this wave's idx block into LDS (coalesced, wave-private) --
    {
        const int* ip = idx + (size_t)R * KNN;
#pragma unroll
        for (int i = 0; i < 5; ++i)
            idxs[wv][lane + i * 64] = ip[lane + i * 64];
    }

    const int c  = lane;
    const float sc = scale_shift[c];
    const float sh = scale_shift[COUT + c];
    float w1p[6];
#pragma unroll
    for (int j = 0; j < 6; ++j) w1p[j] = w1[j * COUT + c] * sc;
    const float b1p = fmaf(b1[c], sc, sh);
    const float dw0 = w1p[0] - w1p[3];
    const float dw1 = w1p[1] - w1p[4];
    const float dw2 = w1p[2] - w1p[5];

    short8 Wh[2][4], Wl[2][4];
#pragma unroll
    for (int t = 0; t < 2; ++t)
#pragma unroll
        for (int n = 0; n < 4; ++n) {
            short8 hv, lv;
#pragma unroll
            for (int jj = 0; jj < 8; ++jj) {
                float w = w2[(t * 32 + g * 8 + jj) * COUT + n * 16 + r15];
                unsigned short hi = f2bf_rn(w);
                unsigned short lo = f2bf_rn(w - bf2f(hi));
                hv[jj] = (short)hi;
                lv[jj] = (short)lo;
            }
            Wh[t][n] = hv;
            Wl[t][n] = lv;
        }

    float base[16];
#pragma unroll
    for (int r = 0; r < 16; ++r) {
        const float* pi = x + (size_t)(R + r) * 3;
        float v = b1p;
        v = fmaf(pi[0], dw0, v);
        v = fmaf(pi[1], dw1, v);
        v = fmaf(pi[2], dw2, v);
        base[r] = v;
    }

    // ---- lane-parallel gather: lane = (row gr) * 4 + (k-slot gk) ----
    const int gr = lane >> 2;        // 0..15: row within wave tile
    const int gk = lane & 3;         // 0..3: k within group
    auto gather_group = [&](int grp) {
        int kk = grp * 4 + gk;
        int j = idxs[wv][gr * KNN + kk];          // per-lane LDS read
        const float* pj = x + (size_t)(bbase + j) * 3;
        sbuf[wv][grp & 1][gk][gr] =
            make_float4(pj[0], pj[1], pj[2], 0.0f);  // 64 indep. loads
    };

    gather_group(0);

    f32x4 mx[4];
#pragma unroll
    for (int n = 0; n < 4; ++n) {
        mx[n][0] = -INFINITY; mx[n][1] = -INFINITY;
        mx[n][2] = -INFINITY; mx[n][3] = -INFINITY;
    }

    unsigned short* hb = &hbuf[wv][0][0];
    const unsigned short* rpnt = hb + r15 * 136;

    for (int grp = 0; grp < 5; ++grp) {
        // issue next group's 64 scattered loads BEFORE consuming this group
        if (grp + 1 < 5) gather_group(grp + 1);

#pragma unroll
        for (int kl = 0; kl < 4; ++kl) {
            // phase 1: h tile from staged coords (uniform broadcast reads)
#pragma unroll
            for (int r = 0; r < 16; ++r) {
                float4 pv = sbuf[wv][grp & 1][kl][r];   // wave-uniform b128
                float h = base[r];
                h = fmaf(pv.x, w1p[3], h);
                h = fmaf(pv.y, w1p[4], h);
                h = fmaf(pv.z, w1p[5], h);
                h = fmaxf(h, 0.0f);
                unsigned hu = __float_as_uint(h);
                unsigned short hi = (unsigned short)(hu >> 16);
                float rem = h - __uint_as_float(hu & 0xFFFF0000u);
                unsigned short lo = (unsigned short)(__float_as_uint(rem) >> 16);
                hb[r * 136 + c]      = hi;
                hb[r * 136 + 64 + c] = lo;
            }

            // phase 2: fragments + MFMA + running max
            short8 Ah0 = *(const short8*)(rpnt + g * 8);
            short8 Ah1 = *(const short8*)(rpnt + 32 + g * 8);
            short8 Al0 = *(const short8*)(rpnt + 64 + g * 8);
            short8 Al1 = *(const short8*)(rpnt + 96 + g * 8);

            __builtin_amdgcn_s_setprio(1);
#pragma unroll
            for (int n = 0; n < 4; ++n) {
                f32x4 a = {0.0f, 0.0f, 0.0f, 0.0f};
                a = __builtin_amdgcn_mfma_f32_16x16x32_bf16(Ah0, Wh[0][n], a, 0, 0, 0);
                a = __builtin_amdgcn_mfma_f32_16x16x32_bf16(Ah1, Wh[1][n], a, 0, 0, 0);
                a = __builtin_amdgcn_mfma_f32_16x16x32_bf16(Al0, Wh[0][n], a, 0, 0, 0);
                a = __builtin_amdgcn_mfma_f32_16x16x32_bf16(Al1, Wh[1][n], a, 0, 0, 0);
                a = __builtin_amdgcn_mfma_f32_16x16x32_bf16(Ah0, Wl[0][n], a, 0, 0, 0);
                a = __builtin_amdgcn_mfma_f32_16x16x32_bf16(Ah1, Wl[1][n], a, 0, 0, 0);
                mx[n][0] = fmaxf(mx[n][0], a[0]);
                mx[n][1] = fmaxf(mx[n][1], a[1]);
                mx[n][2] = fmaxf(mx[n][2], a[2]);
                mx[n][3] = fmaxf(mx[n][3], a[3]);
            }
            __builtin_amdgcn_s_setprio(0);
        }
    }

    float b2v[4];
#pragma unroll
    for (int n = 0; n < 4; ++n) b2v[n] = b2[n * 16 + r15];
#pragma unroll
    for (int n = 0; n < 4; ++n)
#pragma unroll
        for (int rr = 0; rr < 4; ++rr)
            out[(size_t)(R + g * 4 + rr) * COUT + n * 16 + r15] =
                mx[n][rr] + b2v[n];
}

// ===========================================================================
extern "C" void kernel_launch(void* const* d_in, const int* in_sizes, int n_in,
                              void* d_out, int out_size, void* d_ws, size_t ws_size,
                              hipStream_t stream)
{
    const float* x     = (const float*)d_in[0];
    const float* w1    = (const float*)d_in[2];
    const float* b1    = (const float*)d_in[3];
    const float* gamma = (const float*)d_in[4];
    const float* beta  = (const float*)d_in[5];
    const float* w2    = (const float*)d_in[6];
    const float* b2    = (const float*)d_in[7];
    float* out = (float*)d_out;

    char*   ws          = (char*)d_ws;
    double* stats       = (double*)ws;
    float*  scale_shift = (float*)(ws + 256);
    int*    idx         = (int*)(ws + 1024);
    int*    perm        = (int*)(ws + 1024 + (size_t)B_ * N_ * KNN * 4);

    // one-time opt-in for >64KB dynamic LDS; host-side, graph-capture-safe.
    static int _lds_once = []() {
        (void)hipFuncSetAttribute((const void*)knn_f64_kernel,
                                  hipFuncAttributeMaxDynamicSharedMemorySize,
                                  131072);
        return 0;
    }();
    (void)_lds_once;

    morton_bucket_kernel<<<B_, 1024, 0, stream>>>(x, perm, stats);
    knn_f64_kernel<<<dim3(32, 16), 512, 73728, stream>>>(x, perm, idx, stats);
    bn_prep_kernel<<<1, COUT, 0, stream>>>(stats, w1, b1, gamma, beta, scale_shift);
    mlp_max_kernel<<<(B_ * N_) / 64, 256, 0, stream>>>(x, idx, w1, b1, scale_shift,
                                                       w2, b2, out);
}

// Round 13
// 425.724 us; speedup vs baseline: 1.0404x; 1.0282x over previous
//
#include <hip/hip_runtime.h>
#include <math.h>
#include <float.h>

#define B_   16
#define N_   4096
#define CIN  3
#define COUT 64
#define KNN  20
#define EPS_ 1e-5

// ---------------------------------------------------------------------------
// Workspace layout (5.5MB proven-safe footprint):
//   [0,   216): double stats[27]    (Sum e[6], Sum e e^T upper-tri[21])
//   [256, 768): float scale[64], shift[64]
//   [1024, 1024 + B*N*KNN*4): int idx[B*N*KNN]           (5242880 B)
//   [5243904, +B*N*4): int perm[B*N]  (Morton row order)  (262144 B)
//
// r13 change (mlp only; all else byte-identical to r12 = 437.7us):
//   Drop the H-lo plane: C = Hh*(Wh+Wl) with Hh = RTNE-bf16(h). W2 stays
//   hi/lo split (full fp32 weight accuracy). Dropped term = sum rem_d*w_d,
//   |rem_d| <= 2^-9 h_d, zero-mean (RTNE) -> RMS ~3e-3, tail ~0.05 vs
//   threshold 0.194. Saves per k: 8 MFMAs, 16 ds_writes, 2 frag reads,
//   and the lo-extraction VALU. knn noise note: byte-identical knn measured
//   326-356us across r10/r11/r12 -> +-9% run noise band; knn is FROZEN.
// ---------------------------------------------------------------------------

__device__ __forceinline__ unsigned expand10(unsigned v) {
    v = (v | (v << 16)) & 0x030000FFu;
    v = (v | (v << 8))  & 0x0300F00Fu;
    v = (v | (v << 4))  & 0x030C30C3u;
    v = (v | (v << 2))  & 0x09249249u;
    return v;
}
__device__ __forceinline__ unsigned quant10(float v) {
    int q = (int)((v + 4.0f) * 128.0f);
    return (unsigned)min(1023, max(0, q));
}

// ===========================================================================
// Kernel 0: per-batch Morton COUNTING sort (verified) + stats zeroing
// ===========================================================================
__global__ __launch_bounds__(1024) void morton_bucket_kernel(
    const float* __restrict__ x, int* __restrict__ perm,
    double* __restrict__ stats)
{
    __shared__ int hist[1024];
    __shared__ int scanbuf[1024];
    __shared__ int offs[1024];
    const int b = blockIdx.x, tid = threadIdx.x;
    const float* xb = x + (size_t)b * N_ * CIN;

    if (b == 0 && tid < 27) stats[tid] = 0.0;    // replaces hipMemsetAsync;
                                                 // stream-ordered before knn

    hist[tid] = 0;
    __syncthreads();

    int keys[4];
#pragma unroll
    for (int i = 0; i < 4; ++i) {
        int p = tid + i * 1024;
        float v0 = xb[p * 3 + 0], v1 = xb[p * 3 + 1], v2 = xb[p * 3 + 2];
        unsigned m = (expand10(quant10(v0)) << 2) |
                     (expand10(quant10(v1)) << 1) |
                      expand10(quant10(v2));
        keys[i] = (int)(m >> 20);          // top 10 bits
        atomicAdd(&hist[keys[i]], 1);
    }
    __syncthreads();

    int v = hist[tid];
    scanbuf[tid] = v;
    __syncthreads();
    for (int off = 1; off < 1024; off <<= 1) {   // Hillis-Steele inclusive
        int t = (tid >= off) ? scanbuf[tid - off] : 0;
        __syncthreads();
        scanbuf[tid] += t;
        __syncthreads();
    }
    offs[tid] = scanbuf[tid] - v;                // exclusive base
    __syncthreads();

#pragma unroll
    for (int i = 0; i < 4; ++i) {
        int p = tid + i * 1024;
        int pos = atomicAdd(&offs[keys[i]], 1);
        perm[b * N_ + pos] = p;
    }
}

// ===========================================================================
// Kernel 1: exact-match KNN — byte-identical to r10 (verified; frozen).
// ===========================================================================
__global__ __launch_bounds__(512) void knn_f64_kernel(
    const float* __restrict__ x, const int* __restrict__ perm,
    int* __restrict__ idx_out, double* __restrict__ stats)
{
    extern __shared__ __align__(16) char smem[];
    float4* pts = (float4*)smem;                            // {x,y,z,sqj}
    unsigned short* j16 = (unsigned short*)(smem + 65536);  // [4096] orig idx
    double* scr = (double*)smem;                            // merge view

    const int b    = blockIdx.y;
    const int tid  = threadIdx.x;
    const int wave = tid >> 6;
    const int lane = tid & 63;
    const int r    = wave >> 2;     // row-group 0..1
    const int q    = wave & 3;      // interleave class: positions p&3==q
    const float* xb = x + (size_t)b * N_ * CIN;

    for (int p = tid; p < N_; p += 512) {
        int j = perm[b * N_ + p];                // coalesced
        float v0 = xb[j * 3 + 0], v1 = xb[j * 3 + 1], v2 = xb[j * 3 + 2];
        float sq = __fadd_rn(__fadd_rn(__fmul_rn(v0, v0),
                                       __fmul_rn(v1, v1)),
                             __fmul_rn(v2, v2));
        pts[p] = make_float4(v0, v1, v2, sq);
        j16[p] = (unsigned short)j;
    }
    __syncthreads();

    const int rowg = blockIdx.x * 128 + r * 64;  // wave's first row pos
    const float4 xf = pts[rowg + lane];
    const int jrow  = j16[rowg + lane];
    const float sqi = xf.w;                      // staged, bit-identical

    auto mkd = [&](float4 p) -> float {
        float dot = __fadd_rn(__fadd_rn(__fmul_rn(xf.x, p.x),
                                        __fmul_rn(xf.y, p.y)),
                              __fmul_rn(xf.z, p.z));
        return __fsub_rn(__fadd_rn(sqi, p.w), __fmul_rn(2.0f, dot));
    };
    auto sortable = [&](float d) -> unsigned {
        unsigned u = __float_as_uint(d);
        return u ^ (0x80000000u | (unsigned)((int)u >> 31));
    };

    double bk[KNN];
#pragma unroll
    for (int k = 0; k < KNN; ++k) bk[k] = 1e300;     // sentinels (sorted)

    auto insert = [&](double key) {                  // VERBATIM verified
        if (key < bk[KNN - 1]) {
            double m = key;                  // carries max(bk_old[i-1], key)
#pragma unroll
            for (int k = 0; k < KNN; ++k) {
                double old = bk[k];
                bk[k] = fmin(m, old);
                m     = fmax(old, m);
            }
        }
    };

    const int ta = rowg >> 2;            // wave-uniform anchor (SGPR math)
#pragma unroll
    for (int k = 0; k < KNN; ++k) {
        int p = 4 * ((ta + k) & 1023) + q;
        float4 a = pts[p];
        insert(fma((double)sortable(mkd(a)), 4096.0,
                   (double)(unsigned)j16[p]));
    }

    // d19f = exact d of the current 20th-best key (r4-verified decode);
    // refreshed only where bk can change (triggered bodies) -> stale
    // between bodies = over-enter only (insert re-checks the full key).
    float d19f;
    {
        unsigned s19 = (unsigned)trunc(bk[KNN - 1] * (1.0 / 4096.0));
        unsigned u = (s19 >= 0x80000000u) ? (s19 ^ 0x80000000u) : ~s19;
        d19f = __uint_as_float(u);
    }

    for (int s = 0; s < 1024; s += 4) {
        int v0 = ((s + 0) * 509) & 1023;
        int v1 = ((s + 1) * 509) & 1023;
        int v2 = ((s + 2) * 509) & 1023;
        int v3 = ((s + 3) * 509) & 1023;
        int p0 = 4 * ((ta + v0) & 1023) + q;
        int p1 = 4 * ((ta + v1) & 1023) + q;
        int p2 = 4 * ((ta + v2) & 1023) + q;
        int p3 = 4 * ((ta + v3) & 1023) + q;
        float4 a0 = pts[p0];
        float4 a1 = pts[p1];
        float4 a2 = pts[p2];
        float4 a3 = pts[p3];
        float d0 = mkd(a0), d1 = mkd(a1), d2 = mkd(a2), d3 = mkd(a3);
        // prefill positions masked with +INF: its key exceeds any real key.
        d0 = (v0 < 20) ? INFINITY : d0;
        d1 = (v1 < 20) ? INFINITY : d1;
        d2 = (v2 < 20) ? INFINITY : d2;
        d3 = (v3 < 20) ? INFINITY : d3;
        if ((d0 <= d19f) | (d1 <= d19f) | (d2 <= d19f) | (d3 <= d19f)) {
            unsigned j0 = j16[p0], j1 = j16[p1], j2 = j16[p2], j3 = j16[p3];
            insert(fma((double)sortable(d0), 4096.0, (double)j0));
            insert(fma((double)sortable(d1), 4096.0, (double)j1));
            insert(fma((double)sortable(d2), 4096.0, (double)j2));
            insert(fma((double)sortable(d3), 4096.0, (double)j3));
            unsigned s19 = (unsigned)trunc(bk[KNN - 1] * (1.0 / 4096.0));
            unsigned u = (s19 >= 0x80000000u) ? (s19 ^ 0x80000000u) : ~s19;
            d19f = __uint_as_float(u);
        }
    }
    __syncthreads();    // scans done; pts dead (xf in regs) -> scr valid

    if (q & 1) {
        int base = ((r * 2 + (q >> 1)) * 64 + lane) * KNN;
#pragma unroll
        for (int k = 0; k < KNN; ++k) scr[base + k] = bk[k];
    }
    __syncthreads();
    if (!(q & 1)) {                 // q0 absorbs q1; q2 absorbs q3
        int base = ((r * 2 + (q >> 1)) * 64 + lane) * KNN;
#pragma unroll
        for (int k = 0; k < KNN; ++k) insert(scr[base + k]);
    }
    __syncthreads();
    if (q == 2) {
        int base = ((r * 2 + 1) * 64 + lane) * KNN;
#pragma unroll
        for (int k = 0; k < KNN; ++k) scr[base + k] = bk[k];
    }
    __syncthreads();
    if (q == 0) {
        int base = ((r * 2 + 1) * 64 + lane) * KNN;
#pragma unroll
        for (int k = 0; k < KNN; ++k) insert(scr[base + k]);

        const long long row = (long long)b * N_ + jrow;
        int bi[KNN];
#pragma unroll
        for (int k = 0; k < KNN; ++k) {
            double sp = trunc(bk[k] * (1.0 / 4096.0));
            bi[k] = (int)(bk[k] - sp * 4096.0);
        }
#pragma unroll
        for (int k = 0; k < KNN; ++k) idx_out[row * KNN + k] = bi[k];

        float acc[27];
#pragma unroll
        for (int t = 0; t < 27; ++t) acc[t] = 0.0f;
#pragma unroll
        for (int k = 0; k < KNN; ++k) {
            const float* pj = xb + bi[k] * 3;
            float e[6] = { xf.x, xf.y, xf.z,
                           pj[0] - xf.x, pj[1] - xf.y, pj[2] - xf.z };
            int t = 6;
#pragma unroll
            for (int a = 0; a < 6; ++a) {
                acc[a] += e[a];
#pragma unroll
                for (int bb = a; bb < 6; ++bb) acc[t++] += e[a] * e[bb];
            }
        }
#pragma unroll
        for (int t = 0; t < 27; ++t) {
            float v = acc[t];
            v += __shfl_down(v, 32); v += __shfl_down(v, 16);
            v += __shfl_down(v, 8);  v += __shfl_down(v, 4);
            v += __shfl_down(v, 2);  v += __shfl_down(v, 1);
            acc[t] = v;
        }
        if (lane == 0) {
#pragma unroll
            for (int t = 0; t < 27; ++t) atomicAdd(&stats[t], (double)acc[t]);
        }
    }
}

// ===========================================================================
// Kernel 2: fold stats -> per-channel scale/shift (unchanged, verified)
// ===========================================================================
__global__ void bn_prep_kernel(
    const double* __restrict__ stats,
    const float* __restrict__ w1, const float* __restrict__ b1,
    const float* __restrict__ gamma, const float* __restrict__ beta,
    float* __restrict__ scale_shift)
{
    const int c = threadIdx.x;
    double s[6], S[6][6];
#pragma unroll
    for (int a = 0; a < 6; ++a) s[a] = stats[a];
    int t = 6;
#pragma unroll
    for (int a = 0; a < 6; ++a)
#pragma unroll
        for (int bb = a; bb < 6; ++bb) { S[a][bb] = stats[t]; S[bb][a] = stats[t]; ++t; }

    const double M = (double)B_ * N_ * KNN;
    double wc[6];
#pragma unroll
    for (int j = 0; j < 6; ++j) wc[j] = (double)w1[j * COUT + c];
    const double b1c = (double)b1[c];

    double sw = 0.0;
#pragma unroll
    for (int j = 0; j < 6; ++j) sw += s[j] * wc[j];
    double mean = sw / M + b1c;

    double qq = 0.0;
#pragma unroll
    for (int a = 0; a < 6; ++a)
#pragma unroll
        for (int bb = 0; bb < 6; ++bb) qq += S[a][bb] * wc[a] * wc[bb];
    double ex2 = (qq + 2.0 * b1c * sw) / M + b1c * b1c;
    double var = ex2 - mean * mean;

    double sc = (double)gamma[c] / sqrt(var + (double)EPS_);
    double sh = (double)beta[c] - mean * sc;
    scale_shift[c]        = (float)sc;
    scale_shift[COUT + c] = (float)sh;
}

// ===========================================================================
// Kernel 3: fused edge->lin1->BN->ReLU->lin2->max via split-bf16 MFMA.
// r13: H-lo plane dropped (C = Hh*(Wh+Wl), Hh = RTNE-bf16): 16 MFMAs/k,
// 16 ds_writes/k, 2 frag reads/k. Gather pipeline verbatim r12.
// ===========================================================================
typedef __attribute__((ext_vector_type(8))) short short8;
typedef __attribute__((ext_vector_type(4))) float f32x4;

__device__ __forceinline__ unsigned short f2bf_rn(float f) {
    unsigned u = __float_as_uint(f);
    unsigned lsb = (u >> 16) & 1u;
    return (unsigned short)((u + 0x7FFFu + lsb) >> 16);
}
__device__ __forceinline__ float bf2f(unsigned short h) {
    return __uint_as_float(((unsigned)h) << 16);
}

__global__ __launch_bounds__(256) void mlp_max_kernel(
    const float* __restrict__ x, const int* __restrict__ idx,
    const float* __restrict__ w1, const float* __restrict__ b1,
    const float* __restrict__ scale_shift,
    const float* __restrict__ w2, const float* __restrict__ b2,
    float* __restrict__ out)
{
    __shared__ __align__(16) unsigned short hbuf[4][16][136];   // 17.4KB
    __shared__ int idxs[4][320];                                // 5KB
    __shared__ __align__(16) float4 sbuf[4][2][4][16];          // 8KB

    const int tid  = threadIdx.x;
    const int wv   = tid >> 6;
    const int lane = tid & 63;
    const int g    = lane >> 4;      // 16-lane group (k-chunk select)
    const int r15  = lane & 15;      // row (A) / col (B,C) within tile

    const int R     = (blockIdx.x * 4 + wv) * 16;   // wave's first row
    const int bbase = (R >> 12) << 12;              // batch slab start row

    // ---- stage this wave's idx block into LDS (coalesced, wave-private) --
    {
        const int* ip = idx + (size_t)R * KNN;
#pragma unroll
        for (int i = 0; i < 5; ++i)
            idxs[wv][lane + i * 64] = ip[lane + i * 64];
    }

    const int c  = lane;
    const float sc = scale_shift[c];
    const float sh = scale_shift[COUT + c];
    float w1p[6];
#pragma unroll
    for (int j = 0; j < 6; ++j) w1p[j] = w1[j * COUT + c] * sc;
    const float b1p = fmaf(b1[c], sc, sh);
    const float dw0 = w1p[0] - w1p[3];
    const float dw1 = w1p[1] - w1p[4];
    const float dw2 = w1p[2] - w1p[5];

    short8 Wh[2][4], Wl[2][4];
#pragma unroll
    for (int t = 0; t < 2; ++t)
#pragma unroll
        for (int n = 0; n < 4; ++n) {
            short8 hv, lv;
#pragma unroll
            for (int jj = 0; jj < 8; ++jj) {
                float w = w2[(t * 32 + g * 8 + jj) * COUT + n * 16 + r15];
                unsigned short hi = f2bf_rn(w);
                unsigned short lo = f2bf_rn(w - bf2f(hi));
                hv[jj] = (short)hi;
                lv[jj] = (short)lo;
            }
            Wh[t][n] = hv;
            Wl[t][n] = lv;
        }

    float base[16];
#pragma unroll
    for (int r = 0; r < 16; ++r) {
        const float* pi = x + (size_t)(R + r) * 3;
        float v = b1p;
        v = fmaf(pi[0], dw0, v);
        v = fmaf(pi[1], dw1, v);
        v = fmaf(pi[2], dw2, v);
        base[r] = v;
    }

    // ---- lane-parallel gather: lane = (row gr) * 4 + (k-slot gk) ----
    const int gr = lane >> 2;        // 0..15: row within wave tile
    const int gk = lane & 3;         // 0..3: k within group
    auto gather_group = [&](int grp) {
        int kk = grp * 4 + gk;
        int j = idxs[wv][gr * KNN + kk];          // per-lane LDS read
        const float* pj = x + (size_t)(bbase + j) * 3;
        sbuf[wv][grp & 1][gk][gr] =
            make_float4(pj[0], pj[1], pj[2], 0.0f);  // 64 indep. loads
    };

    gather_group(0);

    f32x4 mx[4];
#pragma unroll
    for (int n = 0; n < 4; ++n) {
        mx[n][0] = -INFINITY; mx[n][1] = -INFINITY;
        mx[n][2] = -INFINITY; mx[n][3] = -INFINITY;
    }

    unsigned short* hb = &hbuf[wv][0][0];
    const unsigned short* rpnt = hb + r15 * 136;

    for (int grp = 0; grp < 5; ++grp) {
        // issue next group's 64 scattered loads BEFORE consuming this group
        if (grp + 1 < 5) gather_group(grp + 1);

#pragma unroll
        for (int kl = 0; kl < 4; ++kl) {
            // phase 1: h tile from staged coords; RTNE hi only (lo dropped)
#pragma unroll
            for (int r = 0; r < 16; ++r) {
                float4 pv = sbuf[wv][grp & 1][kl][r];   // wave-uniform b128
                float h = base[r];
                h = fmaf(pv.x, w1p[3], h);
                h = fmaf(pv.y, w1p[4], h);
                h = fmaf(pv.z, w1p[5], h);
                h = fmaxf(h, 0.0f);
                hb[r * 136 + c] = f2bf_rn(h);
            }

            // phase 2: hi fragments + 16 MFMAs + running max
            short8 Ah0 = *(const short8*)(rpnt + g * 8);
            short8 Ah1 = *(const short8*)(rpnt + 32 + g * 8);

            __builtin_amdgcn_s_setprio(1);
#pragma unroll
            for (int n = 0; n < 4; ++n) {
                f32x4 a = {0.0f, 0.0f, 0.0f, 0.0f};
                a = __builtin_amdgcn_mfma_f32_16x16x32_bf16(Ah0, Wh[0][n], a, 0, 0, 0);
                a = __builtin_amdgcn_mfma_f32_16x16x32_bf16(Ah1, Wh[1][n], a, 0, 0, 0);
                a = __builtin_amdgcn_mfma_f32_16x16x32_bf16(Ah0, Wl[0][n], a, 0, 0, 0);
                a = __builtin_amdgcn_mfma_f32_16x16x32_bf16(Ah1, Wl[1][n], a, 0, 0, 0);
                mx[n][0] = fmaxf(mx[n][0], a[0]);
                mx[n][1] = fmaxf(mx[n][1], a[1]);
                mx[n][2] = fmaxf(mx[n][2], a[2]);
                mx[n][3] = fmaxf(mx[n][3], a[3]);
            }
            __builtin_amdgcn_s_setprio(0);
        }
    }

    float b2v[4];
#pragma unroll
    for (int n = 0; n < 4; ++n) b2v[n] = b2[n * 16 + r15];
#pragma unroll
    for (int n = 0; n < 4; ++n)
#pragma unroll
        for (int rr = 0; rr < 4; ++rr)
            out[(size_t)(R + g * 4 + rr) * COUT + n * 16 + r15] =
                mx[n][rr] + b2v[n];
}

// ===========================================================================
extern "C" void kernel_launch(void* const* d_in, const int* in_sizes, int n_in,
                              void* d_out, int out_size, void* d_ws, size_t ws_size,
                              hipStream_t stream)
{
    const float* x     = (const float*)d_in[0];
    const float* w1    = (const float*)d_in[2];
    const float* b1    = (const float*)d_in[3];
    const float* gamma = (const float*)d_in[4];
    const float* beta  = (const float*)d_in[5];
    const float* w2    = (const float*)d_in[6];
    const float* b2    = (const float*)d_in[7];
    float* out = (float*)d_out;

    char*   ws          = (char*)d_ws;
    double* stats       = (double*)ws;
    float*  scale_shift = (float*)(ws + 256);
    int*    idx         = (int*)(ws + 1024);
    int*    perm        = (int*)(ws + 1024 + (size_t)B_ * N_ * KNN * 4);

    // one-time opt-in for >64KB dynamic LDS; host-side, graph-capture-safe.
    static int _lds_once = []() {
        (void)hipFuncSetAttribute((const void*)knn_f64_kernel,
                                  hipFuncAttributeMaxDynamicSharedMemorySize,
                                  131072);
        return 0;
    }();
    (void)_lds_once;

    morton_bucket_kernel<<<B_, 1024, 0, stream>>>(x, perm, stats);
    knn_f64_kernel<<<dim3(32, 16), 512, 73728, stream>>>(x, perm, idx, stats);
    bn_prep_kernel<<<1, COUT, 0, stream>>>(stats, w1, b1, gamma, beta, scale_shift);
    mlp_max_kernel<<<(B_ * N_) / 64, 256, 0, stream>>>(x, idx, w1, b1, scale_shift,
                                                       w2, b2, out);
}